// Round 9
// baseline (158.975 us; speedup 1.0000x reference)
//
#include <hip/hip_runtime.h>

#define CH 64
#define RPB 8
#define BLOCK (RPB * 64)

typedef short short8 __attribute__((ext_vector_type(8)));
typedef float f32x4 __attribute__((ext_vector_type(4)));
typedef unsigned short ushort8v __attribute__((ext_vector_type(8)));

__device__ __forceinline__ unsigned short f2bf(float f) {
    unsigned u = __float_as_uint(f);
    u += 0x7fff + ((u >> 16) & 1);          // round-to-nearest-even
    return (unsigned short)(u >> 16);
}
__device__ __forceinline__ float bf2f(unsigned short h) {
    return __uint_as_float(((unsigned)h) << 16);
}
__device__ __forceinline__ float rl_f(float v, int l) {
    return __uint_as_float(__builtin_amdgcn_readlane(__float_as_uint(v), l));
}

// Kernel A: row_ptr[r] = first edge index e with edge_row[e] >= r  (r in [0, N])
__global__ __launch_bounds__(256) void build_row_ptr(
    const int* __restrict__ erow, int* __restrict__ rp, int N, int E)
{
    int r = blockIdx.x * 256 + threadIdx.x;
    if (r > N) return;
    int lo = 0, len = E;
    while (len > 0) {
        int half = len >> 1;
        int probe = lo + half;
        int v = erow[probe];
        if (v < r) { lo = probe + 1; len -= half + 1; }
        else { len = half; }
    }
    rp[r] = lo;
}

// Kernel A2: precompute W as bf16 hi/lo fragments in mfma_16x16x32 B-layout.
// (validated r8) ws layout: wf[((h*4+ks)*4+nt)*512 + lane*8 + j]
__global__ __launch_bounds__(256) void prep_wfrag(
    const float* __restrict__ W, unsigned short* __restrict__ wf)
{
    int tid = blockIdx.x * 256 + threadIdx.x;
    if (tid >= 2048) return;
    int lane = tid & 63;
    int nt = (tid >> 6) & 3;
    int ks = (tid >> 8) & 3;
    int h  = (tid >> 10) & 1;
    int n  = nt * 16 + (lane & 15);
    int g  = lane >> 4;
    ushort8v o;
    #pragma unroll
    for (int j = 0; j < 8; ++j) {
        int kk = ks * 32 + g * 8 + j;
        float w = (kk < 64) ? W[kk * 64 + n] : W[4096 + (kk - 64) * 64 + n];
        unsigned short hi = f2bf(w);
        o[j] = h ? f2bf(w - bf2f(hi)) : hi;
    }
    *(ushort8v*)(wf + (size_t)tid * 8) = o;
}

// Kernel A3: pack X as interleaved bf16 pairs: Xp[i] = bf16(Xi)<<16 | bf16(Xr)
__global__ __launch_bounds__(256) void pack_x(
    const float* __restrict__ Xr, const float* __restrict__ Xi,
    unsigned* __restrict__ Xp, int total4)
{
    int i = blockIdx.x * 256 + threadIdx.x;
    if (i >= total4) return;
    float4 r  = ((const float4*)Xr)[i];
    float4 im = ((const float4*)Xi)[i];
    uint4 o;
    o.x = ((unsigned)f2bf(im.x) << 16) | f2bf(r.x);
    o.y = ((unsigned)f2bf(im.y) << 16) | f2bf(r.y);
    o.z = ((unsigned)f2bf(im.z) << 16) | f2bf(r.z);
    o.w = ((unsigned)f2bf(im.w) << 16) | f2bf(r.w);
    ((uint4*)Xp)[i] = o;
}

// ---- round-4/8 spmm machinery (PROVEN), PK = packed-bf16 gather variant ----
#define ISSUE(BUF, SB)                                                      \
    do {                                                                    \
        _Pragma("unroll")                                                   \
        for (int j_ = 0; j_ < 8; ++j_) {                                    \
            int c_ = __builtin_amdgcn_readlane(vcol, (SB) * 8 + j_);        \
            if constexpr (PK) {                                             \
                xp##BUF[j_] = Xp[(size_t)c_ * CH + lane];                   \
            } else {                                                        \
                xr##BUF[j_] = Xr[(size_t)c_ * CH + lane];                   \
                xi##BUF[j_] = Xi[(size_t)c_ * CH + lane];                   \
            }                                                               \
        }                                                                   \
        __builtin_amdgcn_sched_barrier(0);                                  \
    } while (0)

#define PROC(BUF, SB)                                                       \
    do {                                                                    \
        _Pragma("unroll")                                                   \
        for (int j_ = 0; j_ < 8; ++j_) {                                    \
            int k_ = (SB) * 8 + j_;                                         \
            float l0r_ = rl_f(vl0r, k_);                                    \
            float l0i_ = rl_f(vl0i, k_);                                    \
            float l1r_ = rl_f(vl1r, k_);                                    \
            float l1i_ = rl_f(vl1i, k_);                                    \
            float xr_, xi_;                                                 \
            if constexpr (PK) {                                             \
                unsigned u_ = xp##BUF[j_];                                  \
                xr_ = __uint_as_float(u_ << 16);                            \
                xi_ = __uint_as_float(u_ & 0xffff0000u);                    \
            } else {                                                        \
                xr_ = xr##BUF[j_]; xi_ = xi##BUF[j_];                       \
            }                                                               \
            a0 += l0r_ * xr_ - l0i_ * xi_;                                  \
            b0 += l0i_ * xr_ + l0r_ * xi_;                                  \
            a1 += l1r_ * xr_ - l1i_ * xi_;                                  \
            b1 += l1i_ * xr_ + l1r_ * xi_;                                  \
        }                                                                   \
    } while (0)

template<int NSB, bool PK>
__device__ __forceinline__ void proc_row(
    int vcol, float vl0r, float vl0i, float vl1r, float vl1i,
    const unsigned* __restrict__ Xp,
    const float* __restrict__ Xr, const float* __restrict__ Xi, int lane,
    float& a0, float& b0, float& a1, float& b1)
{
    unsigned xpA[8], xpB[8];
    float xrA[8], xiA[8], xrB[8], xiB[8];
    ISSUE(A, 0);
    if constexpr (NSB > 1) ISSUE(B, 1);
    PROC(A, 0);
    if constexpr (NSB > 2) ISSUE(A, 2);
    if constexpr (NSB > 1) PROC(B, 1);
    if constexpr (NSB > 3) ISSUE(B, 3);
    if constexpr (NSB > 2) PROC(A, 2);
    if constexpr (NSB > 4) ISSUE(A, 4);
    if constexpr (NSB > 3) PROC(B, 3);
    if constexpr (NSB > 5) ISSUE(B, 5);
    if constexpr (NSB > 4) PROC(A, 4);
    if constexpr (NSB > 6) ISSUE(A, 6);
    if constexpr (NSB > 5) PROC(B, 5);
    if constexpr (NSB > 7) ISSUE(B, 7);
    if constexpr (NSB > 6) PROC(A, 6);
    if constexpr (NSB > 7) PROC(B, 7);
}

// Kernel B: r8 structure verbatim; PK selects packed-bf16 single-dword gathers.
template<bool PK>
__global__ __launch_bounds__(BLOCK, 6) void sdconv_fused(
    const unsigned* __restrict__ Xp,
    const float* __restrict__ Xr, const float* __restrict__ Xi,
    const float* __restrict__ Lr, const float* __restrict__ Li,
    const float* __restrict__ bias,
    const int* __restrict__ ecol, const int* __restrict__ rp,
    const unsigned short* __restrict__ wf,
    float* __restrict__ outR, float* __restrict__ outI,
    int N, int E)
{
    // [arr(4)][blockrow(8)][68]: 0,1 = a0,a1 (real); 2,3 = b0,b1 (imag)
    __shared__ __align__(16) float sA[4 * RPB * 68];  // 8.7 KB

    const int t    = threadIdx.x;
    const int wave = t >> 6;
    const int lane = t & 63;
    const int r0   = blockIdx.x * RPB;
    const int row  = r0 + wave;

    int start = 0, end = 0;
    if (row < N) { start = rp[row]; end = rp[row + 1]; }
    start = __builtin_amdgcn_readfirstlane(start);
    end   = __builtin_amdgcn_readfirstlane(end);

    const float* __restrict__ Lr1 = Lr + E;
    const float* __restrict__ Li1 = Li + E;

    float a0 = 0.f, b0 = 0.f, a1 = 0.f, b1 = 0.f;

    for (int base = start; base < end; base += 64) {
        // one coalesced metadata round for up to 64 edges (lane j = edge j)
        int  eid  = base + lane;
        bool ok   = eid < end;
        int  eidc = ok ? eid : start;
        int   vcol = ecol[eidc];
        float vl0r = ok ? Lr[eidc]  : 0.f;
        float vl0i = ok ? Li[eidc]  : 0.f;
        float vl1r = ok ? Lr1[eidc] : 0.f;
        float vl1i = ok ? Li1[eidc] : 0.f;

        int m = end - base; if (m > 64) m = 64;   // wave-uniform
        int nsb = (m + 7) >> 3;                   // 1..8 sub-batches of 8
        switch (nsb) {
            case 1: proc_row<1, PK>(vcol, vl0r, vl0i, vl1r, vl1i, Xp, Xr, Xi, lane, a0, b0, a1, b1); break;
            case 2: proc_row<2, PK>(vcol, vl0r, vl0i, vl1r, vl1i, Xp, Xr, Xi, lane, a0, b0, a1, b1); break;
            case 3: proc_row<3, PK>(vcol, vl0r, vl0i, vl1r, vl1i, Xp, Xr, Xi, lane, a0, b0, a1, b1); break;
            case 4: proc_row<4, PK>(vcol, vl0r, vl0i, vl1r, vl1i, Xp, Xr, Xi, lane, a0, b0, a1, b1); break;
            case 5: proc_row<5, PK>(vcol, vl0r, vl0i, vl1r, vl1i, Xp, Xr, Xi, lane, a0, b0, a1, b1); break;
            case 6: proc_row<6, PK>(vcol, vl0r, vl0i, vl1r, vl1i, Xp, Xr, Xi, lane, a0, b0, a1, b1); break;
            case 7: proc_row<7, PK>(vcol, vl0r, vl0i, vl1r, vl1i, Xp, Xr, Xi, lane, a0, b0, a1, b1); break;
            default: proc_row<8, PK>(vcol, vl0r, vl0i, vl1r, vl1i, Xp, Xr, Xi, lane, a0, b0, a1, b1); break;
        }
    }

    sA[(0 * RPB + wave) * 68 + lane] = a0;
    sA[(1 * RPB + wave) * 68 + lane] = a1;
    sA[(2 * RPB + wave) * 68 + lane] = b0;
    sA[(3 * RPB + wave) * 68 + lane] = b1;
    __syncthreads();

    // Dual-chain MFMA epilogue (validated r8): waves 0-3 real, 4-7 imag.
    const int nt    = wave & 3;
    const int abase = (wave < 4) ? 0 : 2;
    const int cidx  = lane & 15;
    const int g     = lane >> 4;
    const int ar    = lane & 15;

    f32x4 acc = {0.f, 0.f, 0.f, 0.f};
    #pragma unroll
    for (int ks = 0; ks < 4; ++ks) {
        const int kk0 = ks * 32 + g * 8;
        short8 ah = {0, 0, 0, 0, 0, 0, 0, 0};
        short8 al = {0, 0, 0, 0, 0, 0, 0, 0};
        if (ar < 8) {   // only validated A rows carry data
            const int arr = abase + (kk0 >= 64 ? 1 : 0);
            const float* src = &sA[(arr * RPB + ar) * 68 + (kk0 & 63)];
            float4 v0 = *(const float4*)src;
            float4 v1 = *(const float4*)(src + 4);
            float av[8] = {v0.x, v0.y, v0.z, v0.w, v1.x, v1.y, v1.z, v1.w};
            #pragma unroll
            for (int j = 0; j < 8; ++j) {
                unsigned short hb = f2bf(av[j]);
                ah[j] = (short)hb;
                al[j] = (short)f2bf(av[j] - bf2f(hb));
            }
        }
        short8 bh = *(const short8*)(wf + (size_t)((0 * 4 + ks) * 4 + nt) * 512 + lane * 8);
        short8 bl = *(const short8*)(wf + (size_t)((1 * 4 + ks) * 4 + nt) * 512 + lane * 8);
        acc = __builtin_amdgcn_mfma_f32_16x16x32_bf16(ah, bh, acc, 0, 0, 0);
        acc = __builtin_amdgcn_mfma_f32_16x16x32_bf16(al, bh, acc, 0, 0, 0);
        acc = __builtin_amdgcn_mfma_f32_16x16x32_bf16(ah, bl, acc, 0, 0, 0);
    }

    // C/D: col=lane&15, row=(lane>>4)*4+q -> rows 0-7 live in lanes g<2
    if (g < 2) {
        float bv = bias[nt * 16 + cidx];
        float* dst = (wave < 4) ? outR : outI;
        #pragma unroll
        for (int q = 0; q < 4; ++q) {
            int grow = r0 + g * 4 + q;
            if (grow < N)
                dst[(size_t)grow * CH + nt * 16 + cidx] = acc[q] + bv;
        }
    }
}

extern "C" void kernel_launch(void* const* d_in, const int* in_sizes, int n_in,
                              void* d_out, int out_size, void* d_ws, size_t ws_size,
                              hipStream_t stream)
{
    const float* Xr   = (const float*)d_in[0];
    const float* Xi   = (const float*)d_in[1];
    const float* Lr   = (const float*)d_in[2];
    const float* Li   = (const float*)d_in[3];
    const float* W    = (const float*)d_in[4];
    const float* bias = (const float*)d_in[5];
    const int*   erow = (const int*)d_in[6];
    const int*   ecol = (const int*)d_in[7];

    const int N = in_sizes[0] / CH;
    const int E = in_sizes[6];

    int* rp = (int*)d_ws;
    size_t woff = (((size_t)(N + 1) * 4) + 255) & ~(size_t)255;
    unsigned short* wfrag = (unsigned short*)((char*)d_ws + woff);
    size_t xoff = (woff + 32 * 1024 + 255) & ~(size_t)255;
    unsigned* Xp = (unsigned*)((char*)d_ws + xoff);
    size_t need = xoff + (size_t)N * CH * 4;

    float* outR = (float*)d_out;
    float* outI = outR + (size_t)N * CH;

    hipLaunchKernelGGL(build_row_ptr, dim3((N + 1 + 255) / 256), dim3(256), 0, stream,
                       erow, rp, N, E);
    hipLaunchKernelGGL(prep_wfrag, dim3(8), dim3(256), 0, stream, W, wfrag);

    int nb = (N + RPB - 1) / RPB;
    if (ws_size >= need) {
        int total4 = N * CH / 4;
        hipLaunchKernelGGL(pack_x, dim3((total4 + 255) / 256), dim3(256), 0, stream,
                           Xr, Xi, Xp, total4);
        hipLaunchKernelGGL(sdconv_fused<true>, dim3(nb), dim3(BLOCK), 0, stream,
                           Xp, Xr, Xi, Lr, Li, bias, ecol, rp, wfrag, outR, outI, N, E);
    } else {
        hipLaunchKernelGGL(sdconv_fused<false>, dim3(nb), dim3(BLOCK), 0, stream,
                           (const unsigned*)nullptr, Xr, Xi, Lr, Li, bias, ecol, rp,
                           wfrag, outR, outI, N, E);
    }
}

// Round 10
// 122.836 us; speedup vs baseline: 1.2942x; 1.2942x over previous
//
#include <hip/hip_runtime.h>

#define CH 64
#define RPB 8
#define BLOCK (RPB * 64)

typedef short short8 __attribute__((ext_vector_type(8)));
typedef float f32x4 __attribute__((ext_vector_type(4)));
typedef unsigned short ushort8v __attribute__((ext_vector_type(8)));
typedef _Float16 half2v __attribute__((ext_vector_type(2)));

__device__ __forceinline__ unsigned short f2bf(float f) {
    unsigned u = __float_as_uint(f);
    u += 0x7fff + ((u >> 16) & 1);          // round-to-nearest-even
    return (unsigned short)(u >> 16);
}
__device__ __forceinline__ float bf2f(unsigned short h) {
    return __uint_as_float(((unsigned)h) << 16);
}
// pack two floats as f16 pair: lo = h(a), hi = h(b)
__device__ __forceinline__ unsigned pkh2(float a, float b) {
    union { half2v h; unsigned u; } cv;
    cv.h = half2v{(_Float16)a, (_Float16)b};
    return cv.u;
}
__device__ __forceinline__ half2v u2h2(unsigned u) {
    union { unsigned u; half2v h; } cv;
    cv.u = u;
    return cv.h;
}

// Kernel A: row_ptr[r] = first edge index e with edge_row[e] >= r  (r in [0, N])
__global__ __launch_bounds__(256) void build_row_ptr(
    const int* __restrict__ erow, int* __restrict__ rp, int N, int E)
{
    int r = blockIdx.x * 256 + threadIdx.x;
    if (r > N) return;
    int lo = 0, len = E;
    while (len > 0) {
        int half = len >> 1;
        int probe = lo + half;
        int v = erow[probe];
        if (v < r) { lo = probe + 1; len -= half + 1; }
        else { len = half; }
    }
    rp[r] = lo;
}

// Kernel A2: precompute W as bf16 hi/lo fragments in mfma_16x16x32 B-layout.
// (validated r8) ws layout: wf[((h*4+ks)*4+nt)*512 + lane*8 + j]
__global__ __launch_bounds__(256) void prep_wfrag(
    const float* __restrict__ W, unsigned short* __restrict__ wf)
{
    int tid = blockIdx.x * 256 + threadIdx.x;
    if (tid >= 2048) return;
    int lane = tid & 63;
    int nt = (tid >> 6) & 3;
    int ks = (tid >> 8) & 3;
    int h  = (tid >> 10) & 1;
    int n  = nt * 16 + (lane & 15);
    int g  = lane >> 4;
    ushort8v o;
    #pragma unroll
    for (int j = 0; j < 8; ++j) {
        int kk = ks * 32 + g * 8 + j;
        float w = (kk < 64) ? W[kk * 64 + n] : W[4096 + (kk - 64) * 64 + n];
        unsigned short hi = f2bf(w);
        o[j] = h ? f2bf(w - bf2f(hi)) : hi;
    }
    *(ushort8v*)(wf + (size_t)tid * 8) = o;
}

// Kernel A3: pack X as interleaved f16 pairs: Xp[i] = h(Xi)<<16 | h(Xr)
__global__ __launch_bounds__(256) void pack_x(
    const float* __restrict__ Xr, const float* __restrict__ Xi,
    unsigned* __restrict__ Xp, int total4)
{
    int i = blockIdx.x * 256 + threadIdx.x;
    if (i >= total4) return;
    float4 r  = ((const float4*)Xr)[i];
    float4 im = ((const float4*)Xi)[i];
    uint4 o;
    o.x = pkh2(r.x, im.x);
    o.y = pkh2(r.y, im.y);
    o.z = pkh2(r.z, im.z);
    o.w = pkh2(r.w, im.w);
    ((uint4*)Xp)[i] = o;
}

// ---- spmm machinery (r4/r8 structure); PK = packed-f16 gather + dot2 ----
#define ISSUE(BUF, SB)                                                      \
    do {                                                                    \
        _Pragma("unroll")                                                   \
        for (int j_ = 0; j_ < 8; ++j_) {                                    \
            int c_ = __builtin_amdgcn_readlane(vcol, (SB) * 8 + j_);        \
            if constexpr (PK) {                                             \
                xp##BUF[j_] = Xp[(size_t)c_ * CH + lane];                   \
            } else {                                                        \
                xr##BUF[j_] = Xr[(size_t)c_ * CH + lane];                   \
                xi##BUF[j_] = Xi[(size_t)c_ * CH + lane];                   \
            }                                                               \
        }                                                                   \
        __builtin_amdgcn_sched_barrier(0);                                  \
    } while (0)

#define PROC(BUF, SB)                                                       \
    do {                                                                    \
        _Pragma("unroll")                                                   \
        for (int j_ = 0; j_ < 8; ++j_) {                                    \
            int k_ = (SB) * 8 + j_;                                         \
            if constexpr (PK) {                                             \
                unsigned u0a_ = (unsigned)__builtin_amdgcn_readlane((int)vp0a, k_); \
                unsigned u0b_ = (unsigned)__builtin_amdgcn_readlane((int)vp0b, k_); \
                unsigned u1a_ = (unsigned)__builtin_amdgcn_readlane((int)vp1a, k_); \
                unsigned u1b_ = (unsigned)__builtin_amdgcn_readlane((int)vp1b, k_); \
                half2v xv_ = u2h2(xp##BUF[j_]);                             \
                a0 = __builtin_amdgcn_fdot2(xv_, u2h2(u0a_), a0, false);    \
                b0 = __builtin_amdgcn_fdot2(xv_, u2h2(u0b_), b0, false);    \
                a1 = __builtin_amdgcn_fdot2(xv_, u2h2(u1a_), a1, false);    \
                b1 = __builtin_amdgcn_fdot2(xv_, u2h2(u1b_), b1, false);    \
            } else {                                                        \
                float l0r_ = __uint_as_float(__builtin_amdgcn_readlane(__float_as_uint(vl0r), k_)); \
                float l0i_ = __uint_as_float(__builtin_amdgcn_readlane(__float_as_uint(vl0i), k_)); \
                float l1r_ = __uint_as_float(__builtin_amdgcn_readlane(__float_as_uint(vl1r), k_)); \
                float l1i_ = __uint_as_float(__builtin_amdgcn_readlane(__float_as_uint(vl1i), k_)); \
                a0 += l0r_ * xr##BUF[j_] - l0i_ * xi##BUF[j_];              \
                b0 += l0i_ * xr##BUF[j_] + l0r_ * xi##BUF[j_];              \
                a1 += l1r_ * xr##BUF[j_] - l1i_ * xi##BUF[j_];              \
                b1 += l1i_ * xr##BUF[j_] + l1r_ * xi##BUF[j_];              \
            }                                                               \
        }                                                                   \
    } while (0)

template<int NSB, bool PK>
__device__ __forceinline__ void proc_row(
    int vcol,
    unsigned vp0a, unsigned vp0b, unsigned vp1a, unsigned vp1b,
    float vl0r, float vl0i, float vl1r, float vl1i,
    const unsigned* __restrict__ Xp,
    const float* __restrict__ Xr, const float* __restrict__ Xi, int lane,
    float& a0, float& b0, float& a1, float& b1)
{
    unsigned xpA[8], xpB[8];
    float xrA[8], xiA[8], xrB[8], xiB[8];
    ISSUE(A, 0);
    if constexpr (NSB > 1) ISSUE(B, 1);
    PROC(A, 0);
    if constexpr (NSB > 2) ISSUE(A, 2);
    if constexpr (NSB > 1) PROC(B, 1);
    if constexpr (NSB > 3) ISSUE(B, 3);
    if constexpr (NSB > 2) PROC(A, 2);
    if constexpr (NSB > 4) ISSUE(A, 4);
    if constexpr (NSB > 3) PROC(B, 3);
    if constexpr (NSB > 5) ISSUE(B, 5);
    if constexpr (NSB > 4) PROC(A, 4);
    if constexpr (NSB > 6) ISSUE(A, 6);
    if constexpr (NSB > 5) PROC(B, 5);
    if constexpr (NSB > 7) ISSUE(B, 7);
    if constexpr (NSB > 6) PROC(A, 6);
    if constexpr (NSB > 7) PROC(B, 7);
}

// Kernel B: r8 structure; PK uses f16-pair gathers + v_dot2_f32_f16 inner loop.
template<bool PK>
__global__ __launch_bounds__(BLOCK, 6) void sdconv_fused(
    const unsigned* __restrict__ Xp,
    const float* __restrict__ Xr, const float* __restrict__ Xi,
    const float* __restrict__ Lr, const float* __restrict__ Li,
    const float* __restrict__ bias,
    const int* __restrict__ ecol, const int* __restrict__ rp,
    const unsigned short* __restrict__ wf,
    float* __restrict__ outR, float* __restrict__ outI,
    int N, int E)
{
    // [arr(4)][blockrow(8)][68]: 0,1 = a0,a1 (real); 2,3 = b0,b1 (imag)
    __shared__ __align__(16) float sA[4 * RPB * 68];  // 8.7 KB

    const int t    = threadIdx.x;
    const int wave = t >> 6;
    const int lane = t & 63;
    const int r0   = blockIdx.x * RPB;
    const int row  = r0 + wave;

    int start = 0, end = 0;
    if (row < N) { start = rp[row]; end = rp[row + 1]; }
    start = __builtin_amdgcn_readfirstlane(start);
    end   = __builtin_amdgcn_readfirstlane(end);

    const float* __restrict__ Lr1 = Lr + E;
    const float* __restrict__ Li1 = Li + E;

    float a0 = 0.f, b0 = 0.f, a1 = 0.f, b1 = 0.f;

    for (int base = start; base < end; base += 64) {
        // one coalesced metadata round for up to 64 edges (lane j = edge j)
        int  eid  = base + lane;
        bool ok   = eid < end;
        int  eidc = ok ? eid : start;
        int   vcol = ecol[eidc];
        float vl0r = ok ? Lr[eidc]  : 0.f;
        float vl0i = ok ? Li[eidc]  : 0.f;
        float vl1r = ok ? Lr1[eidc] : 0.f;
        float vl1i = ok ? Li1[eidc] : 0.f;

        // pre-pack per-edge L-coeffs as f16 pairs for the dot2 inner loop
        unsigned vp0a = 0, vp0b = 0, vp1a = 0, vp1b = 0;
        if constexpr (PK) {
            vp0a = pkh2(vl0r, -vl0i);
            vp0b = pkh2(vl0i,  vl0r);
            vp1a = pkh2(vl1r, -vl1i);
            vp1b = pkh2(vl1i,  vl1r);
        }

        int m = end - base; if (m > 64) m = 64;   // wave-uniform
        int nsb = (m + 7) >> 3;                   // 1..8 sub-batches of 8
        switch (nsb) {
            case 1: proc_row<1, PK>(vcol, vp0a, vp0b, vp1a, vp1b, vl0r, vl0i, vl1r, vl1i, Xp, Xr, Xi, lane, a0, b0, a1, b1); break;
            case 2: proc_row<2, PK>(vcol, vp0a, vp0b, vp1a, vp1b, vl0r, vl0i, vl1r, vl1i, Xp, Xr, Xi, lane, a0, b0, a1, b1); break;
            case 3: proc_row<3, PK>(vcol, vp0a, vp0b, vp1a, vp1b, vl0r, vl0i, vl1r, vl1i, Xp, Xr, Xi, lane, a0, b0, a1, b1); break;
            case 4: proc_row<4, PK>(vcol, vp0a, vp0b, vp1a, vp1b, vl0r, vl0i, vl1r, vl1i, Xp, Xr, Xi, lane, a0, b0, a1, b1); break;
            case 5: proc_row<5, PK>(vcol, vp0a, vp0b, vp1a, vp1b, vl0r, vl0i, vl1r, vl1i, Xp, Xr, Xi, lane, a0, b0, a1, b1); break;
            case 6: proc_row<6, PK>(vcol, vp0a, vp0b, vp1a, vp1b, vl0r, vl0i, vl1r, vl1i, Xp, Xr, Xi, lane, a0, b0, a1, b1); break;
            case 7: proc_row<7, PK>(vcol, vp0a, vp0b, vp1a, vp1b, vl0r, vl0i, vl1r, vl1i, Xp, Xr, Xi, lane, a0, b0, a1, b1); break;
            default: proc_row<8, PK>(vcol, vp0a, vp0b, vp1a, vp1b, vl0r, vl0i, vl1r, vl1i, Xp, Xr, Xi, lane, a0, b0, a1, b1); break;
        }
    }

    sA[(0 * RPB + wave) * 68 + lane] = a0;
    sA[(1 * RPB + wave) * 68 + lane] = a1;
    sA[(2 * RPB + wave) * 68 + lane] = b0;
    sA[(3 * RPB + wave) * 68 + lane] = b1;
    __syncthreads();

    // Dual-chain MFMA epilogue (validated r8/r9): waves 0-3 real, 4-7 imag.
    // Trimmed: A used at bf16-hi only; B keeps hi+lo split. Ah*(Bh+Bl).
    const int nt    = wave & 3;
    const int abase = (wave < 4) ? 0 : 2;
    const int cidx  = lane & 15;
    const int g     = lane >> 4;
    const int ar    = lane & 15;

    f32x4 acc = {0.f, 0.f, 0.f, 0.f};
    #pragma unroll
    for (int ks = 0; ks < 4; ++ks) {
        const int kk0 = ks * 32 + g * 8;
        short8 ah = {0, 0, 0, 0, 0, 0, 0, 0};
        if (ar < 8) {   // only validated A rows carry data
            const int arr = abase + (kk0 >= 64 ? 1 : 0);
            const float* src = &sA[(arr * RPB + ar) * 68 + (kk0 & 63)];
            float4 v0 = *(const float4*)src;
            float4 v1 = *(const float4*)(src + 4);
            float av[8] = {v0.x, v0.y, v0.z, v0.w, v1.x, v1.y, v1.z, v1.w};
            #pragma unroll
            for (int j = 0; j < 8; ++j)
                ah[j] = (short)f2bf(av[j]);
        }
        short8 bh = *(const short8*)(wf + (size_t)((0 * 4 + ks) * 4 + nt) * 512 + lane * 8);
        short8 bl = *(const short8*)(wf + (size_t)((1 * 4 + ks) * 4 + nt) * 512 + lane * 8);
        acc = __builtin_amdgcn_mfma_f32_16x16x32_bf16(ah, bh, acc, 0, 0, 0);
        acc = __builtin_amdgcn_mfma_f32_16x16x32_bf16(ah, bl, acc, 0, 0, 0);
    }

    // C/D: col=lane&15, row=(lane>>4)*4+q -> rows 0-7 live in lanes g<2
    if (g < 2) {
        float bv = bias[nt * 16 + cidx];
        float* dst = (wave < 4) ? outR : outI;
        #pragma unroll
        for (int q = 0; q < 4; ++q) {
            int grow = r0 + g * 4 + q;
            if (grow < N)
                dst[(size_t)grow * CH + nt * 16 + cidx] = acc[q] + bv;
        }
    }
}

extern "C" void kernel_launch(void* const* d_in, const int* in_sizes, int n_in,
                              void* d_out, int out_size, void* d_ws, size_t ws_size,
                              hipStream_t stream)
{
    const float* Xr   = (const float*)d_in[0];
    const float* Xi   = (const float*)d_in[1];
    const float* Lr   = (const float*)d_in[2];
    const float* Li   = (const float*)d_in[3];
    const float* W    = (const float*)d_in[4];
    const float* bias = (const float*)d_in[5];
    const int*   erow = (const int*)d_in[6];
    const int*   ecol = (const int*)d_in[7];

    const int N = in_sizes[0] / CH;
    const int E = in_sizes[6];

    int* rp = (int*)d_ws;
    size_t woff = (((size_t)(N + 1) * 4) + 255) & ~(size_t)255;
    unsigned short* wfrag = (unsigned short*)((char*)d_ws + woff);
    size_t xoff = (woff + 32 * 1024 + 255) & ~(size_t)255;
    unsigned* Xp = (unsigned*)((char*)d_ws + xoff);
    size_t need = xoff + (size_t)N * CH * 4;

    float* outR = (float*)d_out;
    float* outI = outR + (size_t)N * CH;

    hipLaunchKernelGGL(build_row_ptr, dim3((N + 1 + 255) / 256), dim3(256), 0, stream,
                       erow, rp, N, E);
    hipLaunchKernelGGL(prep_wfrag, dim3(8), dim3(256), 0, stream, W, wfrag);

    int nb = (N + RPB - 1) / RPB;
    if (ws_size >= need) {
        int total4 = N * CH / 4;
        hipLaunchKernelGGL(pack_x, dim3((total4 + 255) / 256), dim3(256), 0, stream,
                           Xr, Xi, Xp, total4);
        hipLaunchKernelGGL(sdconv_fused<true>, dim3(nb), dim3(BLOCK), 0, stream,
                           Xp, Xr, Xi, Lr, Li, bias, ecol, rp, wfrag, outR, outI, N, E);
    } else {
        hipLaunchKernelGGL(sdconv_fused<false>, dim3(nb), dim3(BLOCK), 0, stream,
                           (const unsigned*)nullptr, Xr, Xi, Lr, Li, bias, ecol, rp,
                           wfrag, outR, outI, N, E);
    }
}